// Round 7
// baseline (676.883 us; speedup 1.0000x reference)
//
#include <hip/hip_runtime.h>
#include <hip/hip_bf16.h>

typedef __attribute__((ext_vector_type(8))) short bf16x8;
typedef __attribute__((ext_vector_type(4))) float f32x4;
typedef __attribute__((ext_vector_type(4))) unsigned int u32x4;

#define KCAT 9216            // 1024 base cols + 1024*8 spline cols
#define NTOK 8192
#define CH   1024
#define KHALF 4608           // split-K half (per kz)
#define BK   64
#define NT   (KHALF / BK)    // 72 K-tiles per block

// ---------- helpers ----------
__device__ __forceinline__ unsigned short f2bf(float f) {
    union { float f; unsigned int u; } v; v.f = f;
    unsigned int r = v.u + 0x7fffu + ((v.u >> 16) & 1u);   // RNE
    return (unsigned short)(r >> 16);
}

__device__ __forceinline__ void load16_to_lds(const void* gp, void* lp) {
    __builtin_amdgcn_global_load_lds(
        (__attribute__((address_space(1))) void*)(void*)gp,
        (__attribute__((address_space(3))) void*)lp,
        16, 0, 0);
}

// Closed-form uniform cubic B-spline (HW-validated round 5): 8 bf16 bases
// packed into w[0..3] for knots t_j = -0.44 + 0.08j.
__device__ __forceinline__ void bases8_cf(float x, unsigned int* w) {
    float p  = (x + 0.44f) * 12.5f;
    float mf = floorf(p);
    float u  = p - mf;
    int   m  = (int)mf;
    float v  = 1.0f - u;
    float u2 = u * u, u3 = u2 * u;
    float N0 = v * v * v * (1.0f / 6.0f);
    float N1 = 0.5f * u3 - u2 + (2.0f / 3.0f);
    float N3 = u3 * (1.0f / 6.0f);
    float N2 = 1.0f - N0 - N1 - N3;
    unsigned long long lo =
          (unsigned long long)f2bf(N0)
        | ((unsigned long long)f2bf(N1) << 16)
        | ((unsigned long long)f2bf(N2) << 32)
        | ((unsigned long long)f2bf(N3) << 48);
    lo = (m >= 0 && m <= 10) ? lo : 0ull;
    int sh  = (m - 3) * 16;
    int sh1 = sh - 64;
    unsigned long long d0 =
        (sh  >= 0) ? ((sh  < 64) ? (lo << sh)    : 0ull)
                   : ((-sh  < 64) ? (lo >> (-sh))  : 0ull);
    unsigned long long d1 =
        (sh1 >= 0) ? ((sh1 < 64) ? (lo << sh1)   : 0ull)
                   : ((-sh1 < 64) ? (lo >> (-sh1)) : 0ull);
    w[0] = (unsigned int)d0; w[1] = (unsigned int)(d0 >> 32);
    w[2] = (unsigned int)d1; w[3] = (unsigned int)(d1 >> 32);
}

// conv_w body: pack one output row o of [base|spline] weights to bf16
__device__ __forceinline__ void conv_w_body(const float* __restrict__ BW,
                                            const float* __restrict__ SW,
                                            unsigned short* __restrict__ W, int o) {
    const float* bw = BW + (size_t)o * 1024;
    const float* sw = SW + (size_t)o * 8192;
    unsigned short* w = W + (size_t)o * KCAT;
    for (int c = threadIdx.x * 4; c < KCAT; c += 256 * 4) {
        const float* src = (c < 1024) ? (bw + c) : (sw + (c - 1024));
        float4 v = *(const float4*)src;
        unsigned short u[4] = { f2bf(v.x), f2bf(v.y), f2bf(v.z), f2bf(v.w) };
        *(unsigned long long*)(w + c) = *(unsigned long long*)u;
    }
}

// basis body: A[n][i]=bf16(x); A[n][1024+8i..+8]=bases
__device__ __forceinline__ void basis_body(float x, unsigned short* __restrict__ A, int idx) {
    int n = idx >> 10, i = idx & 1023;
    size_t rowbase = (size_t)n * KCAT;
    A[rowbase + i] = f2bf(x);
    unsigned int w[4];
    bases8_cf(x, w);
    *(u32x4*)(A + rowbase + 1024 + (size_t)i * 8) = (u32x4){w[0], w[1], w[2], w[3]};
}

// ---------- prep: blocks 0-1023 pack W1; 1024-3071 expand basis(x) ----------
__global__ __launch_bounds__(256) void prep1(const float* __restrict__ BW1,
                                             const float* __restrict__ SW1,
                                             unsigned short* __restrict__ W,
                                             const float* __restrict__ X,
                                             unsigned short* __restrict__ A) {
    int b = blockIdx.x;
    if (b < 1024) { conv_w_body(BW1, SW1, W, b); return; }
    int bb = b - 1024;
    for (int idx = bb * 256 + threadIdx.x; idx < NTOK * CH; idx += 2048 * 256)
        basis_body(X[idx], A, idx);
}

// ---------- mid: blocks 0-1023 pack W2; 1024-3071 expand basis(C0+C1) ----------
__global__ __launch_bounds__(256) void mid2(const float* __restrict__ BW2,
                                            const float* __restrict__ SW2,
                                            unsigned short* __restrict__ W,
                                            const float* __restrict__ C0,
                                            const float* __restrict__ C1,
                                            unsigned short* __restrict__ A) {
    int b = blockIdx.x;
    if (b < 1024) { conv_w_body(BW2, SW2, W, b); return; }
    int bb = b - 1024;
    for (int idx = bb * 256 + threadIdx.x; idx < NTOK * CH; idx += 2048 * 256)
        basis_body(C0[idx] + C1[idx], A, idx);
}

// ---------- final split-K reduction ----------
__global__ __launch_bounds__(256) void add_out(const float* __restrict__ C0,
                                               const float* __restrict__ C1,
                                               float* __restrict__ out, int total4) {
    for (int i = blockIdx.x * 256 + threadIdx.x; i < total4; i += gridDim.x * 256) {
        float4 a = ((const float4*)C0)[i];
        float4 b = ((const float4*)C1)[i];
        float4 r = { a.x + b.x, a.y + b.y, a.z + b.z, a.w + b.w };
        ((float4*)out)[i] = r;
    }
}

// ---------- 256x256 split-K GEMM, round-4 schedule, B reg-staged ----------
// DS-traffic theory: with both operands in LDS, 8-wave 2x4 geometry moves
// 256KB/K-tile through the DS pipe (A re-read 4x, B 2x, stages) -> DS-bound.
// B fragments are only 128B/lane/K-tile: load them straight from global
// (L2-hot W panel), cutting DS traffic to 160KB/K-tile. A path byte-identical
// to round-4 (0 bank conflicts measured).
__global__ __launch_bounds__(512, 2) void gemm256_splitk(const unsigned short* __restrict__ A,
                                                         const unsigned short* __restrict__ B,
                                                         float* __restrict__ C0,
                                                         float* __restrict__ C1) {
    __shared__ __align__(16) unsigned short As[2 * 256 * 64];   // 64 KiB
    const int tid  = threadIdx.x;
    const int lane = tid & 63;
    const int wid  = tid >> 6;
    const int wr = wid >> 2, wc = wid & 3;       // wave grid 2(M) x 4(N)
    const int ln = lane & 15, q = lane >> 4;

    const int bid = blockIdx.x;                  // 0..255, XCD-partitioned
    const int xcd = bid & 7, ii = bid >> 3;
    const int kz = xcd & 1, chm = xcd >> 1;
    const int bm = chm * 8 + (ii & 7);           // 0..31
    const int bn = ii >> 3;                      // 0..3

    const unsigned short* Ab = A + (size_t)(bm * 256) * KCAT + (size_t)kz * KHALF;
    // per-lane B row base: row = bn*256 + wc*64 + nf*16 + ln  (nf added per load)
    const unsigned short* Bl = B + (size_t)(bn * 256 + wc * 64 + ln) * KCAT + (size_t)kz * KHALF;
    float* C = (kz == 0) ? C0 : C1;

    f32x4 acc[8][4] = {};
    bf16x8 bfr[4][2];

    auto stageA = [&](int t, int buf, int part) {
        int chunk = part * 512 + tid;            // 0..2047
        int r = chunk >> 3;                      // row 0..255
        int slot = (chunk & 7) ^ (r & 7);        // inverse swizzle on SOURCE
        size_t goff = (size_t)r * (KCAT * 2) + (size_t)t * 128 + slot * 16;
        load16_to_lds((const char*)Ab + goff, (char*)As + (size_t)buf * 32768 + chunk * 16);
    };
    auto loadB = [&](int t) {                    // 8 x dwordx4 per lane
#pragma unroll
        for (int nf = 0; nf < 4; ++nf)
#pragma unroll
            for (int kh = 0; kh < 2; ++kh)
                bfr[nf][kh] = *(const bf16x8*)(Bl + (size_t)nf * 16 * KCAT
                                                  + (size_t)t * BK + kh * 32 + q * 8);
    };

    // prologue: B(0) to regs, A(0) to LDS buf0
    loadB(0);
    stageA(0, 0, 0); stageA(0, 0, 1); stageA(0, 0, 2); stageA(0, 0, 3);
    asm volatile("s_waitcnt vmcnt(0)" ::: "memory");
    __builtin_amdgcn_s_barrier();

    for (int t = 0; t < NT; ++t) {
        const int c = t & 1;
        const char* Ap = (const char*)As + c * 32768;
        const bool pref = (t + 1 < NT);
#pragma unroll
        for (int p = 0; p < 4; ++p) {
            bf16x8 afr[2][2];
#pragma unroll
            for (int m2 = 0; m2 < 2; ++m2)
#pragma unroll
                for (int kh = 0; kh < 2; ++kh) {
                    int row = wr * 128 + (p * 2 + m2) * 16 + ln;
                    int byte = row * 128 + ((kh * 64 + q * 16) ^ ((row & 7) * 16));
                    afr[m2][kh] = *(const bf16x8*)(Ap + byte);
                }
            if (pref) {
                if (p == 0)      { stageA(t + 1, c ^ 1, 0); stageA(t + 1, c ^ 1, 1); }
                else if (p == 1) { stageA(t + 1, c ^ 1, 2); }
                else if (p == 2) { stageA(t + 1, c ^ 1, 3); }
            }
            __builtin_amdgcn_s_barrier();
            asm volatile("s_waitcnt lgkmcnt(0)" ::: "memory");
            __builtin_amdgcn_sched_barrier(0);
            __builtin_amdgcn_s_setprio(1);
#pragma unroll
            for (int m2 = 0; m2 < 2; ++m2)
#pragma unroll
                for (int nf = 0; nf < 4; ++nf)
#pragma unroll
                    for (int kh = 0; kh < 2; ++kh)
                        acc[p * 2 + m2][nf] = __builtin_amdgcn_mfma_f32_16x16x32_bf16(
                            afr[m2][kh], bfr[nf][kh], acc[p * 2 + m2][nf], 0, 0, 0);
            __builtin_amdgcn_s_setprio(0);
            if (p == 3) {
                asm volatile("s_waitcnt vmcnt(0)" ::: "memory");   // A(t+1) landed
                if (pref) loadB(t + 1);   // bfr free after this tile's last MFMA;
                                          // loads stay in flight across barrier,
                                          // compiler waits them at next p0 use
            }
            __builtin_amdgcn_s_barrier();
        }
    }

    // epilogue: C/D layout col=lane&15, row=(lane>>4)*4+reg [m89-verified]
#pragma unroll
    for (int mf = 0; mf < 8; ++mf)
#pragma unroll
        for (int nf = 0; nf < 4; ++nf)
#pragma unroll
            for (int r = 0; r < 4; ++r) {
                int row = bm * 256 + wr * 128 + mf * 16 + q * 4 + r;
                int col = bn * 256 + wc * 64 + nf * 16 + ln;
                C[(size_t)row * CH + col] = acc[mf][nf][r];
            }
}

// ---------- launch ----------
extern "C" void kernel_launch(void* const* d_in, const int* in_sizes, int n_in,
                              void* d_out, int out_size, void* d_ws, size_t ws_size,
                              hipStream_t stream) {
    const float* x   = (const float*)d_in[0];
    const float* bw1 = (const float*)d_in[1];
    const float* sw1 = (const float*)d_in[2];
    const float* bw2 = (const float*)d_in[3];
    const float* sw2 = (const float*)d_in[4];
    float* out = (float*)d_out;

    char* ws = (char*)d_ws;
    unsigned short* Abuf = (unsigned short*)ws;                    // 150,994,944 B
    unsigned short* Wbuf = (unsigned short*)(ws + 150994944);      //  18,874,368 B
    float* C0 = (float*)(ws + 150994944 + 18874368);               //  33,554,432 B
    float* C1 = (float*)(ws + 150994944 + 18874368 + 33554432);    //  33,554,432 B

    // layer 1
    prep1         <<<dim3(3072), dim3(256), 0, stream>>>(bw1, sw1, Wbuf, x, Abuf);
    gemm256_splitk<<<dim3(256), dim3(512), 0, stream>>>(Abuf, Wbuf, C0, C1);

    // layer 2 (W2 pack + split-K reduce + basis, one kernel)
    mid2          <<<dim3(3072), dim3(256), 0, stream>>>(bw2, sw2, Wbuf, C0, C1, Abuf);
    gemm256_splitk<<<dim3(256), dim3(512), 0, stream>>>(Abuf, Wbuf, C0, C1);
    add_out       <<<dim3(1024), dim3(256), 0, stream>>>(C0, C1, out, NTOK * CH / 4);
}

// Round 8
// 493.420 us; speedup vs baseline: 1.3718x; 1.3718x over previous
//
#include <hip/hip_runtime.h>
#include <hip/hip_bf16.h>

typedef __attribute__((ext_vector_type(8))) short bf16x8;
typedef __attribute__((ext_vector_type(4))) float f32x4;
typedef __attribute__((ext_vector_type(4))) unsigned int u32x4;

#define KCAT 9216            // 1024 base cols + 1024*8 spline cols
#define NTOK 8192
#define CH   1024
#define KHALF 4608           // split-K half (per kz)
#define BK   64
#define NT   (KHALF / BK)    // 72 K-tiles per block

// ---------- helpers ----------
__device__ __forceinline__ unsigned short f2bf(float f) {
    union { float f; unsigned int u; } v; v.f = f;
    unsigned int r = v.u + 0x7fffu + ((v.u >> 16) & 1u);   // RNE
    return (unsigned short)(r >> 16);
}

__device__ __forceinline__ void load16_to_lds(const void* gp, void* lp) {
    __builtin_amdgcn_global_load_lds(
        (__attribute__((address_space(1))) void*)(void*)gp,
        (__attribute__((address_space(3))) void*)lp,
        16, 0, 0);
}

// Closed-form uniform cubic B-spline (HW-validated round 5): 8 bf16 bases
// packed into w[0..3] for knots t_j = -0.44 + 0.08j.
__device__ __forceinline__ void bases8_cf(float x, unsigned int* w) {
    float p  = (x + 0.44f) * 12.5f;
    float mf = floorf(p);
    float u  = p - mf;
    int   m  = (int)mf;
    float v  = 1.0f - u;
    float u2 = u * u, u3 = u2 * u;
    float N0 = v * v * v * (1.0f / 6.0f);
    float N1 = 0.5f * u3 - u2 + (2.0f / 3.0f);
    float N3 = u3 * (1.0f / 6.0f);
    float N2 = 1.0f - N0 - N1 - N3;
    unsigned long long lo =
          (unsigned long long)f2bf(N0)
        | ((unsigned long long)f2bf(N1) << 16)
        | ((unsigned long long)f2bf(N2) << 32)
        | ((unsigned long long)f2bf(N3) << 48);
    lo = (m >= 0 && m <= 10) ? lo : 0ull;
    int sh  = (m - 3) * 16;
    int sh1 = sh - 64;
    unsigned long long d0 =
        (sh  >= 0) ? ((sh  < 64) ? (lo << sh)    : 0ull)
                   : ((-sh  < 64) ? (lo >> (-sh))  : 0ull);
    unsigned long long d1 =
        (sh1 >= 0) ? ((sh1 < 64) ? (lo << sh1)   : 0ull)
                   : ((-sh1 < 64) ? (lo >> (-sh1)) : 0ull);
    w[0] = (unsigned int)d0; w[1] = (unsigned int)(d0 >> 32);
    w[2] = (unsigned int)d1; w[3] = (unsigned int)(d1 >> 32);
}

// conv_w body: pack one output row o of [base|spline] weights to bf16
__device__ __forceinline__ void conv_w_body(const float* __restrict__ BW,
                                            const float* __restrict__ SW,
                                            unsigned short* __restrict__ W, int o) {
    const float* bw = BW + (size_t)o * 1024;
    const float* sw = SW + (size_t)o * 8192;
    unsigned short* w = W + (size_t)o * KCAT;
    for (int c = threadIdx.x * 4; c < KCAT; c += 256 * 4) {
        const float* src = (c < 1024) ? (bw + c) : (sw + (c - 1024));
        float4 v = *(const float4*)src;
        unsigned short u[4] = { f2bf(v.x), f2bf(v.y), f2bf(v.z), f2bf(v.w) };
        *(unsigned long long*)(w + c) = *(unsigned long long*)u;
    }
}

// basis body: A[n][i]=bf16(x); A[n][1024+8i..+8]=bases
__device__ __forceinline__ void basis_body(float x, unsigned short* __restrict__ A, int idx) {
    int n = idx >> 10, i = idx & 1023;
    size_t rowbase = (size_t)n * KCAT;
    A[rowbase + i] = f2bf(x);
    unsigned int w[4];
    bases8_cf(x, w);
    *(u32x4*)(A + rowbase + 1024 + (size_t)i * 8) = (u32x4){w[0], w[1], w[2], w[3]};
}

// ---------- prep: blocks 0-1023 pack W1; 1024-3071 expand basis(x) ----------
__global__ __launch_bounds__(256) void prep1(const float* __restrict__ BW1,
                                             const float* __restrict__ SW1,
                                             unsigned short* __restrict__ W,
                                             const float* __restrict__ X,
                                             unsigned short* __restrict__ A) {
    int b = blockIdx.x;
    if (b < 1024) { conv_w_body(BW1, SW1, W, b); return; }
    int bb = b - 1024;
    for (int idx = bb * 256 + threadIdx.x; idx < NTOK * CH; idx += 2048 * 256)
        basis_body(X[idx], A, idx);
}

// ---------- mid: blocks 0-1023 pack W2; 1024-3071 expand basis(C0+C1) ----------
__global__ __launch_bounds__(256) void mid2(const float* __restrict__ BW2,
                                            const float* __restrict__ SW2,
                                            unsigned short* __restrict__ W,
                                            const float* __restrict__ C0,
                                            const float* __restrict__ C1,
                                            unsigned short* __restrict__ A) {
    int b = blockIdx.x;
    if (b < 1024) { conv_w_body(BW2, SW2, W, b); return; }
    int bb = b - 1024;
    for (int idx = bb * 256 + threadIdx.x; idx < NTOK * CH; idx += 2048 * 256)
        basis_body(C0[idx] + C1[idx], A, idx);
}

// ---------- final split-K reduction ----------
__global__ __launch_bounds__(256) void add_out(const float* __restrict__ C0,
                                               const float* __restrict__ C1,
                                               float* __restrict__ out, int total4) {
    for (int i = blockIdx.x * 256 + threadIdx.x; i < total4; i += gridDim.x * 256) {
        float4 a = ((const float4*)C0)[i];
        float4 b = ((const float4*)C1)[i];
        float4 r = { a.x + b.x, a.y + b.y, a.z + b.z, a.w + b.w };
        ((float4*)out)[i] = r;
    }
}

// ---------- 256x256 split-K GEMM: round-4 base + deep-cover counted staging ----------
// Consumption analysis: B-parts & A-parts{0,2} first read at next-tile p0;
// A-parts{1,3} (rows 64-127 / 192-255) first read at next-tile p2.
// Issue: p0 -> B0..B3, A0, A2 (6 instrs); p1 -> A1, A3 (2 instrs).
// Waits: p1-end vmcnt(8) (current tile's A1/A3, issued last tile p1, ~4-phase
// cover); p3-end vmcnt(2) (next tile's B+A0+A2, ~3-phase cover; A1/A3 stay in
// flight). No wait in the loop has <3 phases of cover -> staging never stalls.
// Read paths, barriers, swizzle byte-identical to round-4 (0 conflicts measured).
__global__ __launch_bounds__(512, 2) void gemm256_splitk(const unsigned short* __restrict__ A,
                                                         const unsigned short* __restrict__ B,
                                                         float* __restrict__ C0,
                                                         float* __restrict__ C1) {
    __shared__ __align__(16) unsigned short As[2 * 256 * 64];
    __shared__ __align__(16) unsigned short Bs[2 * 256 * 64];
    const int tid  = threadIdx.x;
    const int lane = tid & 63;
    const int wid  = tid >> 6;
    const int wr = wid >> 2, wc = wid & 3;       // wave grid 2(M) x 4(N)
    const int ln = lane & 15, q = lane >> 4;

    const int bid = blockIdx.x;                  // 0..255, XCD-partitioned
    const int xcd = bid & 7, ii = bid >> 3;
    const int kz = xcd & 1, chm = xcd >> 1;
    const int bm = chm * 8 + (ii & 7);           // 0..31
    const int bn = ii >> 3;                      // 0..3

    const unsigned short* Ab = A + (size_t)(bm * 256) * KCAT + (size_t)kz * KHALF;
    const unsigned short* Bb = B + (size_t)(bn * 256) * KCAT + (size_t)kz * KHALF;
    float* C = (kz == 0) ? C0 : C1;

    f32x4 acc[8][4] = {};

    auto stageA = [&](int t, int buf, int part) {
        int chunk = part * 512 + tid;            // 0..2047
        int r = chunk >> 3;                      // row 0..255
        int slot = (chunk & 7) ^ (r & 7);        // inverse swizzle on SOURCE
        size_t goff = (size_t)r * (KCAT * 2) + (size_t)t * 128 + slot * 16;
        load16_to_lds((const char*)Ab + goff, (char*)As + (size_t)buf * 32768 + chunk * 16);
    };
    auto stageB = [&](int t, int buf, int part) {
        int chunk = part * 512 + tid;
        int r = chunk >> 3;
        int slot = (chunk & 7) ^ (r & 7);
        size_t goff = (size_t)r * (KCAT * 2) + (size_t)t * 128 + slot * 16;
        load16_to_lds((const char*)Bb + goff, (char*)Bs + (size_t)buf * 32768 + chunk * 16);
    };

    // prologue: tile 0 -> buf 0, full drain
#pragma unroll
    for (int part = 0; part < 4; ++part) stageB(0, 0, part);
#pragma unroll
    for (int part = 0; part < 4; ++part) stageA(0, 0, part);
    asm volatile("s_waitcnt vmcnt(0)" ::: "memory");
    __builtin_amdgcn_s_barrier();

    for (int t = 0; t < NT; ++t) {
        const int c = t & 1;
        const char* Ap = (const char*)As + c * 32768;
        const char* Bp = (const char*)Bs + c * 32768;
        const bool pref = (t + 1 < NT);
        bf16x8 bfr[4][2];
#pragma unroll
        for (int p = 0; p < 4; ++p) {
            bf16x8 afr[2][2];
#pragma unroll
            for (int m2 = 0; m2 < 2; ++m2)
#pragma unroll
                for (int kh = 0; kh < 2; ++kh) {
                    int row = wr * 128 + (p * 2 + m2) * 16 + ln;
                    int byte = row * 128 + ((kh * 64 + q * 16) ^ ((row & 7) * 16));
                    afr[m2][kh] = *(const bf16x8*)(Ap + byte);
                }
            if (p == 0) {
#pragma unroll
                for (int nf = 0; nf < 4; ++nf)
#pragma unroll
                    for (int kh = 0; kh < 2; ++kh) {
                        int row = wc * 64 + nf * 16 + ln;
                        int byte = row * 128 + ((kh * 64 + q * 16) ^ ((row & 7) * 16));
                        bfr[nf][kh] = *(const bf16x8*)(Bp + byte);
                    }
            }
            // staging for tile t+1 -> buf c^1 (issue-early, wait-late)
            if (pref) {
                if (p == 0) {
                    stageB(t + 1, c ^ 1, 0); stageB(t + 1, c ^ 1, 1);
                    stageB(t + 1, c ^ 1, 2); stageB(t + 1, c ^ 1, 3);
                    stageA(t + 1, c ^ 1, 0); stageA(t + 1, c ^ 1, 2);
                } else if (p == 1) {
                    stageA(t + 1, c ^ 1, 1); stageA(t + 1, c ^ 1, 3);
                }
            }
            __builtin_amdgcn_s_barrier();
            asm volatile("s_waitcnt lgkmcnt(0)" ::: "memory");
            __builtin_amdgcn_sched_barrier(0);
            __builtin_amdgcn_s_setprio(1);
#pragma unroll
            for (int m2 = 0; m2 < 2; ++m2)
#pragma unroll
                for (int nf = 0; nf < 4; ++nf)
#pragma unroll
                    for (int kh = 0; kh < 2; ++kh)
                        acc[p * 2 + m2][nf] = __builtin_amdgcn_mfma_f32_16x16x32_bf16(
                            afr[m2][kh], bfr[nf][kh], acc[p * 2 + m2][nf], 0, 0, 0);
            __builtin_amdgcn_s_setprio(0);
            if (p == 1) {
                // current tile's A-parts 1,3 (read at p2) landed; issued last
                // tile p1 -> ~4-phase cover. Last tile: full drain (no-op cost).
                if (pref) asm volatile("s_waitcnt vmcnt(8)" ::: "memory");
                else      asm volatile("s_waitcnt vmcnt(0)" ::: "memory");
            } else if (p == 3) {
                // t+1's B + A0,A2 (read at next p0) landed, ~3-phase cover;
                // t+1's A1,A3 stay in flight (waited at next tile's p1).
                if (pref) asm volatile("s_waitcnt vmcnt(2)" ::: "memory");
                else      asm volatile("s_waitcnt vmcnt(0)" ::: "memory");
            }
            __builtin_amdgcn_s_barrier();
        }
    }

    // epilogue: C/D layout col=lane&15, row=(lane>>4)*4+reg [m89-verified]
#pragma unroll
    for (int mf = 0; mf < 8; ++mf)
#pragma unroll
        for (int nf = 0; nf < 4; ++nf)
#pragma unroll
            for (int r = 0; r < 4; ++r) {
                int row = bm * 256 + wr * 128 + mf * 16 + q * 4 + r;
                int col = bn * 256 + wc * 64 + nf * 16 + ln;
                C[(size_t)row * CH + col] = acc[mf][nf][r];
            }
}

// ---------- launch ----------
extern "C" void kernel_launch(void* const* d_in, const int* in_sizes, int n_in,
                              void* d_out, int out_size, void* d_ws, size_t ws_size,
                              hipStream_t stream) {
    const float* x   = (const float*)d_in[0];
    const float* bw1 = (const float*)d_in[1];
    const float* sw1 = (const float*)d_in[2];
    const float* bw2 = (const float*)d_in[3];
    const float* sw2 = (const float*)d_in[4];
    float* out = (float*)d_out;

    char* ws = (char*)d_ws;
    unsigned short* Abuf = (unsigned short*)ws;                    // 150,994,944 B
    unsigned short* Wbuf = (unsigned short*)(ws + 150994944);      //  18,874,368 B
    float* C0 = (float*)(ws + 150994944 + 18874368);               //  33,554,432 B
    float* C1 = (float*)(ws + 150994944 + 18874368 + 33554432);    //  33,554,432 B

    // layer 1
    prep1         <<<dim3(3072), dim3(256), 0, stream>>>(bw1, sw1, Wbuf, x, Abuf);
    gemm256_splitk<<<dim3(256), dim3(512), 0, stream>>>(Abuf, Wbuf, C0, C1);

    // layer 2 (W2 pack + split-K reduce + basis, one kernel)
    mid2          <<<dim3(3072), dim3(256), 0, stream>>>(bw2, sw2, Wbuf, C0, C1, Abuf);
    gemm256_splitk<<<dim3(256), dim3(512), 0, stream>>>(Abuf, Wbuf, C0, C1);
    add_out       <<<dim3(1024), dim3(256), 0, stream>>>(C0, C1, out, NTOK * CH / 4);
}

// Round 9
// 488.799 us; speedup vs baseline: 1.3848x; 1.0095x over previous
//
#include <hip/hip_runtime.h>
#include <hip/hip_bf16.h>

typedef __attribute__((ext_vector_type(8))) short bf16x8;
typedef __attribute__((ext_vector_type(4))) float f32x4;
typedef __attribute__((ext_vector_type(4))) unsigned int u32x4;

#define KCAT 9216            // 1024 base cols + 1024*8 spline cols
#define NTOK 8192
#define CH   1024
#define KHALF 4608           // split-K half (per kz)
#define NT32 144             // K=32 tiles per block (4608/32)

// ---------- helpers ----------
__device__ __forceinline__ unsigned short f2bf(float f) {
    union { float f; unsigned int u; } v; v.f = f;
    unsigned int r = v.u + 0x7fffu + ((v.u >> 16) & 1u);   // RNE
    return (unsigned short)(r >> 16);
}

__device__ __forceinline__ void load16_to_lds(const void* gp, void* lp) {
    __builtin_amdgcn_global_load_lds(
        (__attribute__((address_space(1))) void*)(void*)gp,
        (__attribute__((address_space(3))) void*)lp,
        16, 0, 0);
}

// Closed-form uniform cubic B-spline (HW-validated round 5)
__device__ __forceinline__ void bases8_cf(float x, unsigned int* w) {
    float p  = (x + 0.44f) * 12.5f;
    float mf = floorf(p);
    float u  = p - mf;
    int   m  = (int)mf;
    float v  = 1.0f - u;
    float u2 = u * u, u3 = u2 * u;
    float N0 = v * v * v * (1.0f / 6.0f);
    float N1 = 0.5f * u3 - u2 + (2.0f / 3.0f);
    float N3 = u3 * (1.0f / 6.0f);
    float N2 = 1.0f - N0 - N1 - N3;
    unsigned long long lo =
          (unsigned long long)f2bf(N0)
        | ((unsigned long long)f2bf(N1) << 16)
        | ((unsigned long long)f2bf(N2) << 32)
        | ((unsigned long long)f2bf(N3) << 48);
    lo = (m >= 0 && m <= 10) ? lo : 0ull;
    int sh  = (m - 3) * 16;
    int sh1 = sh - 64;
    unsigned long long d0 =
        (sh  >= 0) ? ((sh  < 64) ? (lo << sh)    : 0ull)
                   : ((-sh  < 64) ? (lo >> (-sh))  : 0ull);
    unsigned long long d1 =
        (sh1 >= 0) ? ((sh1 < 64) ? (lo << sh1)   : 0ull)
                   : ((-sh1 < 64) ? (lo >> (-sh1)) : 0ull);
    w[0] = (unsigned int)d0; w[1] = (unsigned int)(d0 >> 32);
    w[2] = (unsigned int)d1; w[3] = (unsigned int)(d1 >> 32);
}

__device__ __forceinline__ void conv_w_body(const float* __restrict__ BW,
                                            const float* __restrict__ SW,
                                            unsigned short* __restrict__ W, int o) {
    const float* bw = BW + (size_t)o * 1024;
    const float* sw = SW + (size_t)o * 8192;
    unsigned short* w = W + (size_t)o * KCAT;
    for (int c = threadIdx.x * 4; c < KCAT; c += 256 * 4) {
        const float* src = (c < 1024) ? (bw + c) : (sw + (c - 1024));
        float4 v = *(const float4*)src;
        unsigned short u[4] = { f2bf(v.x), f2bf(v.y), f2bf(v.z), f2bf(v.w) };
        *(unsigned long long*)(w + c) = *(unsigned long long*)u;
    }
}

__device__ __forceinline__ void basis_body(float x, unsigned short* __restrict__ A, int idx) {
    int n = idx >> 10, i = idx & 1023;
    size_t rowbase = (size_t)n * KCAT;
    A[rowbase + i] = f2bf(x);
    unsigned int w[4];
    bases8_cf(x, w);
    *(u32x4*)(A + rowbase + 1024 + (size_t)i * 8) = (u32x4){w[0], w[1], w[2], w[3]};
}

// ---------- prep: blocks 0-1023 pack W1; 1024-3071 expand basis(x) ----------
__global__ __launch_bounds__(256) void prep1(const float* __restrict__ BW1,
                                             const float* __restrict__ SW1,
                                             unsigned short* __restrict__ W,
                                             const float* __restrict__ X,
                                             unsigned short* __restrict__ A) {
    int b = blockIdx.x;
    if (b < 1024) { conv_w_body(BW1, SW1, W, b); return; }
    int bb = b - 1024;
    for (int idx = bb * 256 + threadIdx.x; idx < NTOK * CH; idx += 2048 * 256)
        basis_body(X[idx], A, idx);
}

// ---------- mid: blocks 0-1023 pack W2; 1024-3071 expand basis(C0+C1) ----------
__global__ __launch_bounds__(256) void mid2(const float* __restrict__ BW2,
                                            const float* __restrict__ SW2,
                                            unsigned short* __restrict__ W,
                                            const float* __restrict__ C0,
                                            const float* __restrict__ C1,
                                            unsigned short* __restrict__ A) {
    int b = blockIdx.x;
    if (b < 1024) { conv_w_body(BW2, SW2, W, b); return; }
    int bb = b - 1024;
    for (int idx = bb * 256 + threadIdx.x; idx < NTOK * CH; idx += 2048 * 256)
        basis_body(C0[idx] + C1[idx], A, idx);
}

// ---------- final split-K reduction ----------
__global__ __launch_bounds__(256) void add_out(const float* __restrict__ C0,
                                               const float* __restrict__ C1,
                                               float* __restrict__ out, int total4) {
    for (int i = blockIdx.x * 256 + threadIdx.x; i < total4; i += gridDim.x * 256) {
        float4 a = ((const float4*)C0)[i];
        float4 b = ((const float4*)C1)[i];
        float4 r = { a.x + b.x, a.y + b.y, a.z + b.z, a.w + b.w };
        ((float4*)out)[i] = r;
    }
}

// ---------- 256x256 split-K GEMM: de-convoyed 4-buffer BK=32 ring ----------
// Theory (r4/r6/r7/r8 evidence): the 2-barrier-per-phase convoy locks both
// waves/SIMD into the same phase -> matrix pipe idles during DS bursts;
// MfmaUtil capped ~44%. Here: ONE vmcnt(4)+barrier per K32-tile, no intra-tile
// sync, plain ds_reads (compiler emits fine-grained lgkmcnt), stage(t+2)
// issued at tile start (2-tile cover). Waves drift anti-phase -> DS overlaps
// MFMA. Hazard ledger: reads of tile t safe after barrier(t-1) (vmcnt chain
// forces t's loads landed); earliest rewrite of buf[t&3] is stage(t+4) issued
// in tile t+2, after all waves passed barrier(t+1) i.e. finished reading t.
// Memory layout + swizzle byte-identical to round-6 (measured 0 conflicts).
__global__ __launch_bounds__(512, 2) void gemm256_splitk(const unsigned short* __restrict__ A,
                                                         const unsigned short* __restrict__ B,
                                                         float* __restrict__ C0,
                                                         float* __restrict__ C1) {
    __shared__ __align__(16) unsigned short As[4 * 256 * 32];   // 64 KiB, 4 bufs
    __shared__ __align__(16) unsigned short Bs[4 * 256 * 32];   // 64 KiB
    const int tid  = threadIdx.x;
    const int lane = tid & 63;
    const int wid  = tid >> 6;
    const int wr = wid >> 2, wc = wid & 3;       // wave grid 2(M) x 4(N)
    const int ln = lane & 15, q = lane >> 4;

    const int bid = blockIdx.x;                  // 0..255, XCD-partitioned
    const int xcd = bid & 7, ii = bid >> 3;
    const int kz = xcd & 1, chm = xcd >> 1;
    const int bm = chm * 8 + (ii & 7);           // 0..31
    const int bn = ii >> 3;                      // 0..3

    const unsigned short* Ab = A + (size_t)(bm * 256) * KCAT + (size_t)kz * KHALF;
    const unsigned short* Bb = B + (size_t)(bn * 256) * KCAT + (size_t)kz * KHALF;
    float* C = (kz == 0) ? C0 : C1;

    f32x4 acc[8][4] = {};

    // stage one K32-tile (16KB A + 16KB B) -> buffer ds; 4 vmem instrs/thread
    auto stage = [&](int tile, int ds) {
#pragma unroll
        for (int part = 0; part < 2; ++part) {
            int c = part * 512 + tid;            // 0..1023
            int r = c >> 2;                      // row 0..255
            int gslot = (c & 3) ^ ((r >> 1) & 3);
            size_t goff = (size_t)r * (KCAT * 2) + (size_t)tile * 64 + gslot * 16;
            load16_to_lds((const char*)Ab + goff, (char*)As + (size_t)ds * 16384 + c * 16);
            load16_to_lds((const char*)Bb + goff, (char*)Bs + (size_t)ds * 16384 + c * 16);
        }
    };

    // prologue: tiles 0,1 -> bufs 0,1; wait tile0 (tile1's 4 stay in flight)
    stage(0, 0);
    stage(1, 1);
    asm volatile("s_waitcnt vmcnt(4)" ::: "memory");
    __builtin_amdgcn_s_barrier();

    for (int g = 0; g < NT32 / 4; ++g) {
#pragma unroll
        for (int u = 0; u < 4; ++u) {
            const int tile = g * 4 + u;          // buffer index = u (compile-time)
            const bool pf = (tile + 2) < NT32;
            if (pf) stage(tile + 2, (u + 2) & 3);

            const char* Ah = (const char*)As + u * 16384;
            const char* Bh = (const char*)Bs + u * 16384;
            bf16x8 afr[8], bfr[4];
#pragma unroll
            for (int f = 0; f < 8; ++f) {
                int row = wr * 128 + f * 16 + ln;
                afr[f] = *(const bf16x8*)(Ah + row * 64 + ((q ^ ((row >> 1) & 3)) * 16));
            }
#pragma unroll
            for (int nf = 0; nf < 4; ++nf) {
                int row = wc * 64 + nf * 16 + ln;
                bfr[nf] = *(const bf16x8*)(Bh + row * 64 + ((q ^ ((row >> 1) & 3)) * 16));
            }
            __builtin_amdgcn_s_setprio(1);
#pragma unroll
            for (int f = 0; f < 8; ++f)
#pragma unroll
                for (int nf = 0; nf < 4; ++nf)
                    acc[f][nf] = __builtin_amdgcn_mfma_f32_16x16x32_bf16(
                        afr[f], bfr[nf], acc[f][nf], 0, 0, 0);
            __builtin_amdgcn_s_setprio(0);
            // publish: tile+1's loads landed (tile+2's 4 stay in flight)
            if (pf) asm volatile("s_waitcnt vmcnt(4)" ::: "memory");
            else    asm volatile("s_waitcnt vmcnt(0)" ::: "memory");
            __builtin_amdgcn_s_barrier();
        }
    }

    // epilogue: C/D layout col=lane&15, row=(lane>>4)*4+reg [m89-verified]
#pragma unroll
    for (int mf = 0; mf < 8; ++mf)
#pragma unroll
        for (int nf = 0; nf < 4; ++nf)
#pragma unroll
            for (int r = 0; r < 4; ++r) {
                int row = bm * 256 + wr * 128 + mf * 16 + q * 4 + r;
                int col = bn * 256 + wc * 64 + nf * 16 + ln;
                C[(size_t)row * CH + col] = acc[mf][nf][r];
            }
}

// ---------- launch ----------
extern "C" void kernel_launch(void* const* d_in, const int* in_sizes, int n_in,
                              void* d_out, int out_size, void* d_ws, size_t ws_size,
                              hipStream_t stream) {
    const float* x   = (const float*)d_in[0];
    const float* bw1 = (const float*)d_in[1];
    const float* sw1 = (const float*)d_in[2];
    const float* bw2 = (const float*)d_in[3];
    const float* sw2 = (const float*)d_in[4];
    float* out = (float*)d_out;

    char* ws = (char*)d_ws;
    unsigned short* Abuf = (unsigned short*)ws;                    // 150,994,944 B
    unsigned short* Wbuf = (unsigned short*)(ws + 150994944);      //  18,874,368 B
    float* C0 = (float*)(ws + 150994944 + 18874368);               //  33,554,432 B
    float* C1 = (float*)(ws + 150994944 + 18874368 + 33554432);    //  33,554,432 B

    // layer 1
    prep1         <<<dim3(3072), dim3(256), 0, stream>>>(bw1, sw1, Wbuf, x, Abuf);
    gemm256_splitk<<<dim3(256), dim3(512), 0, stream>>>(Abuf, Wbuf, C0, C1);

    // layer 2 (W2 pack + split-K reduce + basis, one kernel)
    mid2          <<<dim3(3072), dim3(256), 0, stream>>>(bw2, sw2, Wbuf, C0, C1, Abuf);
    gemm256_splitk<<<dim3(256), dim3(512), 0, stream>>>(Abuf, Wbuf, C0, C1);
    add_out       <<<dim3(1024), dim3(256), 0, stream>>>(C0, C1, out, NTOK * CH / 4);
}

// Round 10
// 485.509 us; speedup vs baseline: 1.3942x; 1.0068x over previous
//
#include <hip/hip_runtime.h>
#include <hip/hip_bf16.h>

typedef __attribute__((ext_vector_type(8))) short bf16x8;
typedef __attribute__((ext_vector_type(4))) float f32x4;
typedef __attribute__((ext_vector_type(4))) unsigned int u32x4;

#define KCAT 9216            // 1024 base cols + 1024*8 spline cols
#define NTOK 8192
#define CH   1024
#define KHALF 4608           // split-K half (per kz)
#define NT32 144             // K=32 tiles per block (4608/32)

// ---------- helpers ----------
__device__ __forceinline__ unsigned short f2bf(float f) {
    union { float f; unsigned int u; } v; v.f = f;
    unsigned int r = v.u + 0x7fffu + ((v.u >> 16) & 1u);   // RNE
    return (unsigned short)(r >> 16);
}

__device__ __forceinline__ void load16_to_lds(const void* gp, void* lp) {
    __builtin_amdgcn_global_load_lds(
        (__attribute__((address_space(1))) void*)(void*)gp,
        (__attribute__((address_space(3))) void*)lp,
        16, 0, 0);
}

// Closed-form uniform cubic B-spline (HW-validated round 5)
__device__ __forceinline__ void bases8_cf(float x, unsigned int* w) {
    float p  = (x + 0.44f) * 12.5f;
    float mf = floorf(p);
    float u  = p - mf;
    int   m  = (int)mf;
    float v  = 1.0f - u;
    float u2 = u * u, u3 = u2 * u;
    float N0 = v * v * v * (1.0f / 6.0f);
    float N1 = 0.5f * u3 - u2 + (2.0f / 3.0f);
    float N3 = u3 * (1.0f / 6.0f);
    float N2 = 1.0f - N0 - N1 - N3;
    unsigned long long lo =
          (unsigned long long)f2bf(N0)
        | ((unsigned long long)f2bf(N1) << 16)
        | ((unsigned long long)f2bf(N2) << 32)
        | ((unsigned long long)f2bf(N3) << 48);
    lo = (m >= 0 && m <= 10) ? lo : 0ull;
    int sh  = (m - 3) * 16;
    int sh1 = sh - 64;
    unsigned long long d0 =
        (sh  >= 0) ? ((sh  < 64) ? (lo << sh)    : 0ull)
                   : ((-sh  < 64) ? (lo >> (-sh))  : 0ull);
    unsigned long long d1 =
        (sh1 >= 0) ? ((sh1 < 64) ? (lo << sh1)   : 0ull)
                   : ((-sh1 < 64) ? (lo >> (-sh1)) : 0ull);
    w[0] = (unsigned int)d0; w[1] = (unsigned int)(d0 >> 32);
    w[2] = (unsigned int)d1; w[3] = (unsigned int)(d1 >> 32);
}

__device__ __forceinline__ void conv_w_body(const float* __restrict__ BW,
                                            const float* __restrict__ SW,
                                            unsigned short* __restrict__ W, int o) {
    const float* bw = BW + (size_t)o * 1024;
    const float* sw = SW + (size_t)o * 8192;
    unsigned short* w = W + (size_t)o * KCAT;
    for (int c = threadIdx.x * 4; c < KCAT; c += 256 * 4) {
        const float* src = (c < 1024) ? (bw + c) : (sw + (c - 1024));
        float4 v = *(const float4*)src;
        unsigned short u[4] = { f2bf(v.x), f2bf(v.y), f2bf(v.z), f2bf(v.w) };
        *(unsigned long long*)(w + c) = *(unsigned long long*)u;
    }
}

__device__ __forceinline__ void basis_body(float x, unsigned short* __restrict__ A, int idx) {
    int n = idx >> 10, i = idx & 1023;
    size_t rowbase = (size_t)n * KCAT;
    A[rowbase + i] = f2bf(x);
    unsigned int w[4];
    bases8_cf(x, w);
    *(u32x4*)(A + rowbase + 1024 + (size_t)i * 8) = (u32x4){w[0], w[1], w[2], w[3]};
}

// ---------- prep: blocks 0-1023 pack W1; 1024-3071 expand basis(x) ----------
__global__ __launch_bounds__(256) void prep1(const float* __restrict__ BW1,
                                             const float* __restrict__ SW1,
                                             unsigned short* __restrict__ W,
                                             const float* __restrict__ X,
                                             unsigned short* __restrict__ A) {
    int b = blockIdx.x;
    if (b < 1024) { conv_w_body(BW1, SW1, W, b); return; }
    int bb = b - 1024;
    for (int idx = bb * 256 + threadIdx.x; idx < NTOK * CH; idx += 2048 * 256)
        basis_body(X[idx], A, idx);
}

// ---------- mid: blocks 0-1023 pack W2; 1024-3071 expand basis(C0+C1) ----------
__global__ __launch_bounds__(256) void mid2(const float* __restrict__ BW2,
                                            const float* __restrict__ SW2,
                                            unsigned short* __restrict__ W,
                                            const float* __restrict__ C0,
                                            const float* __restrict__ C1,
                                            unsigned short* __restrict__ A) {
    int b = blockIdx.x;
    if (b < 1024) { conv_w_body(BW2, SW2, W, b); return; }
    int bb = b - 1024;
    for (int idx = bb * 256 + threadIdx.x; idx < NTOK * CH; idx += 2048 * 256)
        basis_body(C0[idx] + C1[idx], A, idx);
}

// ---------- final split-K reduction ----------
__global__ __launch_bounds__(256) void add_out(const float* __restrict__ C0,
                                               const float* __restrict__ C1,
                                               float* __restrict__ out, int total4) {
    for (int i = blockIdx.x * 256 + threadIdx.x; i < total4; i += gridDim.x * 256) {
        float4 a = ((const float4*)C0)[i];
        float4 b = ((const float4*)C1)[i];
        float4 r = { a.x + b.x, a.y + b.y, a.z + b.z, a.w + b.w };
        ((float4*)out)[i] = r;
    }
}

// ---------- 256x256 split-K GEMM: r9 ring + interleaved {ds,MFMA} emission ----------
// r4/r8/r9 all ~150us @43% MfmaUtil: per-tile time = DS(1400cy) + MFMA(1242cy)
// SUM, not max -- in-phase waves burst 12 ds_reads together, DS pipe idles
// during the joint MFMA burst. Fix: 4 groups {reads; 8 MFMA} pinned with
// sched_group_barrier so each group's reads hide under the prior cluster's
// MFMAs. Sync/ring/swizzle byte-identical to r9 (verified ledger, 0 conflicts).
__global__ __launch_bounds__(512, 2) void gemm256_splitk(const unsigned short* __restrict__ A,
                                                         const unsigned short* __restrict__ B,
                                                         float* __restrict__ C0,
                                                         float* __restrict__ C1) {
    __shared__ __align__(16) unsigned short As[4 * 256 * 32];   // 64 KiB, 4 bufs
    __shared__ __align__(16) unsigned short Bs[4 * 256 * 32];   // 64 KiB
    const int tid  = threadIdx.x;
    const int lane = tid & 63;
    const int wid  = tid >> 6;
    const int wr = wid >> 2, wc = wid & 3;       // wave grid 2(M) x 4(N)
    const int ln = lane & 15, q = lane >> 4;

    const int bid = blockIdx.x;                  // 0..255, XCD-partitioned
    const int xcd = bid & 7, ii = bid >> 3;
    const int kz = xcd & 1, chm = xcd >> 1;
    const int bm = chm * 8 + (ii & 7);           // 0..31
    const int bn = ii >> 3;                      // 0..3

    const unsigned short* Ab = A + (size_t)(bm * 256) * KCAT + (size_t)kz * KHALF;
    const unsigned short* Bb = B + (size_t)(bn * 256) * KCAT + (size_t)kz * KHALF;
    float* C = (kz == 0) ? C0 : C1;

    f32x4 acc[8][4] = {};

    // stage one K32-tile (16KB A + 16KB B) -> buffer ds; 4 vmem instrs/thread
    auto stage = [&](int tile, int ds) {
#pragma unroll
        for (int part = 0; part < 2; ++part) {
            int c = part * 512 + tid;            // 0..1023
            int r = c >> 2;                      // row 0..255
            int gslot = (c & 3) ^ ((r >> 1) & 3);
            size_t goff = (size_t)r * (KCAT * 2) + (size_t)tile * 64 + gslot * 16;
            load16_to_lds((const char*)Ab + goff, (char*)As + (size_t)ds * 16384 + c * 16);
            load16_to_lds((const char*)Bb + goff, (char*)Bs + (size_t)ds * 16384 + c * 16);
        }
    };

    // prologue: tiles 0,1 -> bufs 0,1; wait tile0 (tile1's 4 stay in flight)
    stage(0, 0);
    stage(1, 1);
    asm volatile("s_waitcnt vmcnt(4)" ::: "memory");
    __builtin_amdgcn_s_barrier();

    for (int g = 0; g < NT32 / 4; ++g) {
#pragma unroll
        for (int u = 0; u < 4; ++u) {
            const int tile = g * 4 + u;          // buffer index = u (compile-time)
            const bool pf = (tile + 2) < NT32;
            if (pf) stage(tile + 2, (u + 2) & 3);

            const char* Ah = (const char*)As + u * 16384;
            const char* Bh = (const char*)Bs + u * 16384;
            bf16x8 afr[8], bfr[4];
            // G1 reads: all B frags + afr0,1 (feeds cluster f0,f1)
#pragma unroll
            for (int nf = 0; nf < 4; ++nf) {
                int row = wc * 64 + nf * 16 + ln;
                bfr[nf] = *(const bf16x8*)(Bh + row * 64 + ((q ^ ((row >> 1) & 3)) * 16));
            }
#pragma unroll
            for (int f = 0; f < 8; ++f) {
                int row = wr * 128 + f * 16 + ln;
                afr[f] = *(const bf16x8*)(Ah + row * 64 + ((q ^ ((row >> 1) & 3)) * 16));
            }
            // clusters: C_g uses afr[2g],afr[2g+1] x bfr[0..3]
#pragma unroll
            for (int f = 0; f < 8; ++f)
#pragma unroll
                for (int nf = 0; nf < 4; ++nf)
                    acc[f][nf] = __builtin_amdgcn_mfma_f32_16x16x32_bf16(
                        afr[f], bfr[nf], acc[f][nf], 0, 0, 0);

            // pin emission: [4 VMEM][6 DS][8 MFMA][2 DS][8 MFMA][2 DS][8 MFMA][2 DS][8 MFMA]
            __builtin_amdgcn_sched_group_barrier(0x020, 4, 0);  // global_load_lds
            __builtin_amdgcn_sched_group_barrier(0x100, 6, 0);  // bfr0-3, afr0-1
            __builtin_amdgcn_sched_group_barrier(0x008, 8, 0);  // f0,f1
            __builtin_amdgcn_sched_group_barrier(0x100, 2, 0);  // afr2-3
            __builtin_amdgcn_sched_group_barrier(0x008, 8, 0);  // f2,f3
            __builtin_amdgcn_sched_group_barrier(0x100, 2, 0);  // afr4-5
            __builtin_amdgcn_sched_group_barrier(0x008, 8, 0);  // f4,f5
            __builtin_amdgcn_sched_group_barrier(0x100, 2, 0);  // afr6-7
            __builtin_amdgcn_sched_group_barrier(0x008, 8, 0);  // f6,f7

            // publish: tile+1's loads landed (tile+2's 4 stay in flight)
            if (pf) asm volatile("s_waitcnt vmcnt(4)" ::: "memory");
            else    asm volatile("s_waitcnt vmcnt(0)" ::: "memory");
            __builtin_amdgcn_s_barrier();
        }
    }

    // epilogue: C/D layout col=lane&15, row=(lane>>4)*4+reg [m89-verified]
#pragma unroll
    for (int mf = 0; mf < 8; ++mf)
#pragma unroll
        for (int nf = 0; nf < 4; ++nf)
#pragma unroll
            for (int r = 0; r < 4; ++r) {
                int row = bm * 256 + wr * 128 + mf * 16 + q * 4 + r;
                int col = bn * 256 + wc * 64 + nf * 16 + ln;
                C[(size_t)row * CH + col] = acc[mf][nf][r];
            }
}

// ---------- launch ----------
extern "C" void kernel_launch(void* const* d_in, const int* in_sizes, int n_in,
                              void* d_out, int out_size, void* d_ws, size_t ws_size,
                              hipStream_t stream) {
    const float* x   = (const float*)d_in[0];
    const float* bw1 = (const float*)d_in[1];
    const float* sw1 = (const float*)d_in[2];
    const float* bw2 = (const float*)d_in[3];
    const float* sw2 = (const float*)d_in[4];
    float* out = (float*)d_out;

    char* ws = (char*)d_ws;
    unsigned short* Abuf = (unsigned short*)ws;                    // 150,994,944 B
    unsigned short* Wbuf = (unsigned short*)(ws + 150994944);      //  18,874,368 B
    float* C0 = (float*)(ws + 150994944 + 18874368);               //  33,554,432 B
    float* C1 = (float*)(ws + 150994944 + 18874368 + 33554432);    //  33,554,432 B

    // layer 1
    prep1         <<<dim3(3072), dim3(256), 0, stream>>>(bw1, sw1, Wbuf, x, Abuf);
    gemm256_splitk<<<dim3(256), dim3(512), 0, stream>>>(Abuf, Wbuf, C0, C1);

    // layer 2 (W2 pack + split-K reduce + basis, one kernel)
    mid2          <<<dim3(3072), dim3(256), 0, stream>>>(bw2, sw2, Wbuf, C0, C1, Abuf);
    gemm256_splitk<<<dim3(256), dim3(512), 0, stream>>>(Abuf, Wbuf, C0, C1);
    add_out       <<<dim3(1024), dim3(256), 0, stream>>>(C0, C1, out, NTOK * CH / 4);
}